// Round 2
// baseline (588.690 us; speedup 1.0000x reference)
//
#include <hip/hip_runtime.h>
#include <stdint.h>

// ---------------------------------------------------------------------------
// HolographicThoracicMemory on MI355X (gfx950)
// Restructure: interference_weight[b,k] = s^T M_k s,
//   M_k = (0.42*1.8/256) * sum_c ref[k,c,:] (x) obj[k,c,:]
// All GEMMs via mfma_f32_16x16x32_bf16 (fp32 accumulate).
// ---------------------------------------------------------------------------

typedef __attribute__((ext_vector_type(4))) float f32x4;
typedef __attribute__((ext_vector_type(8))) short s16x8;

#define SCALE_IW 0.002953125f  // 0.42 * 1.8 / 256

__device__ __forceinline__ ushort f2bf(float f) {
  uint32_t u = __builtin_bit_cast(uint32_t, f);
  u += 0x7fffu + ((u >> 16) & 1u);   // round-to-nearest-even
  return (ushort)(u >> 16);
}
__device__ __forceinline__ float bf2f(ushort u) {
  return __builtin_bit_cast(float, ((uint32_t)u) << 16);
}
__device__ __forceinline__ void gl_lds16(const ushort* g, ushort* l) {
  __builtin_amdgcn_global_load_lds(
      (const __attribute__((address_space(1))) uint32_t*)g,
      (__attribute__((address_space(3))) uint32_t*)l, 16, 0, 0);
}
__device__ __forceinline__ f32x4 mfma16(s16x8 a, s16x8 b, f32x4 c) {
  return __builtin_amdgcn_mfma_f32_16x16x32_bf16(a, b, c, 0, 0, 0);
}

// ---------------------------------------------------------------------------
// Prep: batched tiled transpose fp32 -> bf16.  src [S][R][C] -> dst [S][C][R]
// grid (C/64, R/64, S), block (64,4)
// ---------------------------------------------------------------------------
__global__ __launch_bounds__(256) void k_transpose(const float* __restrict__ src,
                                                   ushort* __restrict__ dst,
                                                   int R, int C) {
  __shared__ float tile[64][65];
  const int s = blockIdx.z;
  src += (size_t)s * R * C;
  dst += (size_t)s * R * C;
  const int c0 = blockIdx.x * 64, r0 = blockIdx.y * 64;
  const int tx = threadIdx.x, ty = threadIdx.y;
  for (int i = ty; i < 64; i += 4)
    tile[i][tx] = src[(size_t)(r0 + i) * C + (c0 + tx)];
  __syncthreads();
  for (int i = ty; i < 64; i += 4)
    dst[(size_t)(c0 + i) * R + (r0 + tx)] = f2bf(tile[tx][i]);
}

// ---------------------------------------------------------------------------
// Prep: MT[k][e][d] = SCALE_IW * sum_c ref[k][c][d] * obj[k][c][e]   (bf16)
// grid (16, 14), block 128 (d)
// ---------------------------------------------------------------------------
__global__ __launch_bounds__(128) void k_build_mt(const float* __restrict__ ref,
                                                  const float* __restrict__ obj,
                                                  ushort* __restrict__ mt) {
  const int k = blockIdx.y, e0 = blockIdx.x * 8, d = threadIdx.x;
  const float* rp = ref + (size_t)k * 256 * 128;
  const float* op = obj + (size_t)k * 256 * 128;
  float acc[8] = {};
  for (int c = 0; c < 256; ++c) {
    const float rv = rp[c * 128 + d];
#pragma unroll
    for (int j = 0; j < 8; ++j) acc[j] += rv * op[c * 128 + e0 + j];
  }
  ushort* o = mt + (size_t)k * 128 * 128;
#pragma unroll
  for (int j = 0; j < 8; ++j) o[(e0 + j) * 128 + d] = f2bf(acc[j] * SCALE_IW);
}

// ---------------------------------------------------------------------------
// GEMM1: X[B,3200] (concat of 3 fp32 sources, converted bf16 in staging)
//        @ W1T[256 n][3200 k] bf16  -> relu(+b1) -> H1[B,256] bf16
// grid 512 (32 rows each), block 256 = 4 waves; wave tile 32x64; K-step 32.
// ---------------------------------------------------------------------------
__global__ __launch_bounds__(256, 2) void k_gemm1(
    const float* __restrict__ sup, const float* __restrict__ anom,
    const float* __restrict__ ind, const ushort* __restrict__ w1t,
    const float* __restrict__ b1, ushort* __restrict__ h1) {
  __shared__ alignas(16) ushort As[32 * 40];       // [row][k] stride 40 (pad)
  __shared__ alignas(16) ushort Bs[4 * 256 * 8];   // [kchunk][n][8]
  const int t = threadIdx.x;
  const int w = t >> 6, l = t & 63, m = l & 15, q = l >> 4;
  const int b0 = blockIdx.x * 32;
  const int ar = t >> 3, ac = t & 7;
  f32x4 acc[2][4] = {};
  for (int ks = 0; ks < 100; ++ks) {
    const int k0 = ks * 32;
    const float* src;
    int rs, koff;
    if (k0 < 1024)      { src = sup;  rs = 1024; koff = k0; }
    else if (k0 < 1152) { src = anom; rs = 128;  koff = k0 - 1024; }
    else                { src = ind;  rs = 2048; koff = k0 - 1152; }
    const float4 v = *(const float4*)(src + (size_t)(b0 + ar) * rs + koff + ac * 4);
#pragma unroll
    for (int i = 0; i < 4; ++i)
      gl_lds16(w1t + (size_t)t * 3200 + k0 + i * 8, Bs + i * 2048 + t * 8);
    uint2 pk;
    pk.x = (uint)f2bf(v.x) | ((uint)f2bf(v.y) << 16);
    pk.y = (uint)f2bf(v.z) | ((uint)f2bf(v.w) << 16);
    *(uint2*)(As + ar * 40 + ac * 4) = pk;
    __syncthreads();
    s16x8 af[2], bf[4];
#pragma unroll
    for (int rt = 0; rt < 2; ++rt)
      af[rt] = *(const s16x8*)(As + (rt * 16 + m) * 40 + q * 8);
#pragma unroll
    for (int ct = 0; ct < 4; ++ct)
      bf[ct] = *(const s16x8*)(Bs + q * 2048 + (w * 64 + ct * 16 + m) * 8);
#pragma unroll
    for (int rt = 0; rt < 2; ++rt)
#pragma unroll
      for (int ct = 0; ct < 4; ++ct)
        acc[rt][ct] = mfma16(af[rt], bf[ct], acc[rt][ct]);
    __syncthreads();
  }
#pragma unroll
  for (int ct = 0; ct < 4; ++ct) {
    const int col = w * 64 + ct * 16 + m;
    const float bias = b1[col];
#pragma unroll
    for (int rt = 0; rt < 2; ++rt)
#pragma unroll
      for (int r = 0; r < 4; ++r) {
        const int row = b0 + rt * 16 + q * 4 + r;
        h1[(size_t)row * 256 + col] = f2bf(fmaxf(acc[rt][ct][r] + bias, 0.f));
      }
  }
}

// ---------------------------------------------------------------------------
// Consolidator: H1[B,256] -> relu(.@W2+b2) -> 12x relu(.@Wl+bl) -> state[B,128]
// grid 256 (64 rows each), block 256 = 4 waves; wave tile 64x32 per layer.
// Ping-pong LDS selected by ternary (NOT a pointer array — addrspace(3)
// pointer arrays fail to compile on gfx950).
// ---------------------------------------------------------------------------
__global__ __launch_bounds__(256, 1) void k_cons(
    const ushort* __restrict__ h1, const ushort* __restrict__ w2t,
    const ushort* __restrict__ cwt, const float* __restrict__ b2,
    const float* __restrict__ cb, ushort* __restrict__ stateg) {
  __shared__ alignas(16) ushort A0[64 * 264];      // layer-0 input, stride 264
  __shared__ alignas(16) ushort S0[64 * 136];      // state ping, stride 136
  __shared__ alignas(16) ushort S1[64 * 136];      // state pong
  __shared__ alignas(16) ushort Wb[16 * 128 * 8];  // [kchunk][n][8] (32 KB)
  const int t = threadIdx.x;
  const int w = t >> 6, l = t & 63, m = l & 15, q = l >> 4;
  const int b0 = blockIdx.x * 64;
#pragma unroll
  for (int i = 0; i < 8; ++i) {
    const int s = i * 256 + t, r = s >> 5, c = s & 31;
    *(uint4*)(A0 + r * 264 + c * 8) =
        *(const uint4*)(h1 + (size_t)(b0 + r) * 256 + c * 8);
  }
  for (int layer = 0; layer <= 12; ++layer) {
    // parity: layer 0 writes S0; odd layers read S0/write S1; even read S1/write S0
    const ushort* Asrc;
    int astr, K;
    const ushort* wsrc;
    const float* bias;
    if (layer == 0) {
      Asrc = A0; astr = 264; wsrc = w2t; bias = b2; K = 256;
    } else {
      Asrc = (layer & 1) ? (const ushort*)S0 : (const ushort*)S1;
      astr = 136;
      wsrc = cwt + (size_t)(layer - 1) * 16384;
      bias = cb + (layer - 1) * 128; K = 128;
    }
    ushort* dst = (layer & 1) ? S1 : S0;
    f32x4 acc[4][2] = {};
    const int halves = K >> 7;
    for (int h = 0; h < halves; ++h) {
#pragma unroll
      for (int i = 0; i < 8; ++i) {
        const int s = i * 256 + t, c = s >> 7, n = s & 127;
        gl_lds16(wsrc + (size_t)n * K + h * 128 + c * 8, Wb + c * 1024 + n * 8);
      }
      __syncthreads();
#pragma unroll
      for (int ks = 0; ks < 4; ++ks) {
        s16x8 af[4];
        const int kc = h * 16 + ks * 4 + q;
#pragma unroll
        for (int rt = 0; rt < 4; ++rt)
          af[rt] = *(const s16x8*)(Asrc + (rt * 16 + m) * astr + kc * 8);
#pragma unroll
        for (int ct = 0; ct < 2; ++ct) {
          const s16x8 bf =
              *(const s16x8*)(Wb + (ks * 4 + q) * 1024 + (w * 32 + ct * 16 + m) * 8);
#pragma unroll
          for (int rt = 0; rt < 4; ++rt)
            acc[rt][ct] = mfma16(af[rt], bf, acc[rt][ct]);
        }
      }
      __syncthreads();
    }
#pragma unroll
    for (int ct = 0; ct < 2; ++ct) {
      const int col = w * 32 + ct * 16 + m;
      const float bv = bias[col];
#pragma unroll
      for (int rt = 0; rt < 4; ++rt)
#pragma unroll
        for (int r = 0; r < 4; ++r)
          dst[(rt * 16 + q * 4 + r) * 136 + col] =
              f2bf(fmaxf(acc[rt][ct][r] + bv, 0.f));
    }
    __syncthreads();
  }
  const ushort* fin = S0;  // layer 12 (even) wrote S0
#pragma unroll
  for (int i = 0; i < 4; ++i) {
    const int s = i * 256 + t, r = s >> 4, c = s & 15;
    *(uint4*)(stateg + (size_t)(b0 + r) * 128 + c * 8) =
        *(const uint4*)(fin + r * 136 + c * 8);
  }
}

// ---------------------------------------------------------------------------
// Banks: per k: P = S@MT_k (for iw = s^T M_k s), R = S@retWT_k; epilogue
//   out[b,k,e] = (iw[b,k] + 0.3*mean|anom_b|) * (R[b,e] + ret_b[k,e])
// grid 256 (64 rows), block 256 = 4 waves; wave tile 64x32 per panel.
// ---------------------------------------------------------------------------
__global__ __launch_bounds__(256, 1) void k_banks(
    const ushort* __restrict__ stateg, const float* __restrict__ anom,
    const ushort* __restrict__ mt, const ushort* __restrict__ rwt,
    const float* __restrict__ retb, float* __restrict__ out) {
  __shared__ alignas(16) ushort S[64 * 136];
  __shared__ alignas(16) ushort Mb[16 * 128 * 8];
  __shared__ alignas(16) ushort Rb[16 * 128 * 8];
  __shared__ alignas(16) float retbs[14 * 128];
  __shared__ alignas(16) float iwbuf[4][64];
  __shared__ alignas(16) float wvs[64];
  __shared__ alignas(16) float aws[64];
  const int t = threadIdx.x;
  const int w = t >> 6, l = t & 63, m = l & 15, q = l >> 4;
  const int b0 = blockIdx.x * 64;
#pragma unroll
  for (int i = 0; i < 4; ++i) {
    const int s = i * 256 + t, r = s >> 4, c = s & 15;
    *(uint4*)(S + r * 136 + c * 8) =
        *(const uint4*)(stateg + (size_t)(b0 + r) * 128 + c * 8);
  }
  for (int i = t; i < 14 * 128; i += 256) retbs[i] = retb[i];
  {
    const int r = t >> 2, qq = t & 3;
    float sa = 0.f;
#pragma unroll
    for (int j = 0; j < 8; ++j) {
      const float4 v =
          *(const float4*)(anom + (size_t)(b0 + r) * 128 + qq * 32 + j * 4);
      sa += fabsf(v.x) + fabsf(v.y) + fabsf(v.z) + fabsf(v.w);
    }
    sa += __shfl_xor(sa, 1, 4);
    sa += __shfl_xor(sa, 2, 4);
    if (qq == 0) aws[r] = sa * (0.3f / 128.f);
  }
  __syncthreads();
  // persistent A fragments (state) + fp32 copy of s matched to C-layout lanes
  s16x8 af[4][4];  // [ks][rt]
#pragma unroll
  for (int ks = 0; ks < 4; ++ks)
#pragma unroll
    for (int rt = 0; rt < 4; ++rt)
      af[ks][rt] = *(const s16x8*)(S + (rt * 16 + m) * 136 + (ks * 4 + q) * 8);
  float sc[4][4][2];  // [rt][reg][ct]
#pragma unroll
  for (int rt = 0; rt < 4; ++rt)
#pragma unroll
    for (int r = 0; r < 4; ++r)
#pragma unroll
      for (int ct = 0; ct < 2; ++ct)
        sc[rt][r][ct] =
            bf2f(S[(rt * 16 + q * 4 + r) * 136 + (w * 32 + ct * 16 + m)]);
  for (int k = 0; k < 14; ++k) {
#pragma unroll
    for (int i = 0; i < 8; ++i) {
      const int s = i * 256 + t, c = s >> 7, n = s & 127;
      gl_lds16(mt + (size_t)k * 16384 + n * 128 + c * 8, Mb + c * 1024 + n * 8);
      gl_lds16(rwt + (size_t)k * 16384 + n * 128 + c * 8, Rb + c * 1024 + n * 8);
    }
    __syncthreads();
    f32x4 P[4][2] = {}, R[4][2] = {};
#pragma unroll
    for (int ks = 0; ks < 4; ++ks)
#pragma unroll
      for (int ct = 0; ct < 2; ++ct) {
        const int boff = (ks * 4 + q) * 1024 + (w * 32 + ct * 16 + m) * 8;
        const s16x8 bm = *(const s16x8*)(Mb + boff);
        const s16x8 br = *(const s16x8*)(Rb + boff);
#pragma unroll
        for (int rt = 0; rt < 4; ++rt) {
          P[rt][ct] = mfma16(af[ks][rt], bm, P[rt][ct]);
          R[rt][ct] = mfma16(af[ks][rt], br, R[rt][ct]);
        }
      }
    // iw row-dot: reduce P * s over columns (16 lanes share a quad-row set)
#pragma unroll
    for (int rt = 0; rt < 4; ++rt) {
      float pr[4];
#pragma unroll
      for (int r = 0; r < 4; ++r) {
        float v = P[rt][0][r] * sc[rt][r][0] + P[rt][1][r] * sc[rt][r][1];
        v += __shfl_xor(v, 1, 16);
        v += __shfl_xor(v, 2, 16);
        v += __shfl_xor(v, 4, 16);
        v += __shfl_xor(v, 8, 16);
        pr[r] = v;
      }
      if (m == 0)
        *(float4*)&iwbuf[w][rt * 16 + q * 4] =
            make_float4(pr[0], pr[1], pr[2], pr[3]);
    }
    __syncthreads();
    if (t < 64)
      wvs[t] = iwbuf[0][t] + iwbuf[1][t] + iwbuf[2][t] + iwbuf[3][t] + aws[t];
    __syncthreads();
#pragma unroll
    for (int ct = 0; ct < 2; ++ct) {
      const int col = w * 32 + ct * 16 + m;
      const float rb = retbs[k * 128 + col];
#pragma unroll
      for (int rt = 0; rt < 4; ++rt) {
        const float4 wv4 = *(const float4*)&wvs[rt * 16 + q * 4];
        const float wvv[4] = {wv4.x, wv4.y, wv4.z, wv4.w};
#pragma unroll
        for (int r = 0; r < 4; ++r) {
          const int row = b0 + rt * 16 + q * 4 + r;
          out[(size_t)row * 1792 + k * 128 + col] = wvv[r] * (R[rt][ct][r] + rb);
        }
      }
    }
    // no trailing barrier needed: next-k LDS writes (Mb/Rb) are ordered after
    // this k's reads by the two collective barriers above; wvs/iwbuf writes in
    // k+1 also sit behind those barriers.
  }
}

// ---------------------------------------------------------------------------
extern "C" void kernel_launch(void* const* d_in, const int* in_sizes, int n_in,
                              void* d_out, int out_size, void* d_ws,
                              size_t ws_size, hipStream_t stream) {
  const float* sup   = (const float*)d_in[0];
  const float* anom  = (const float*)d_in[1];
  const float* ind   = (const float*)d_in[2];
  const float* ipW1  = (const float*)d_in[3];
  const float* ipb1  = (const float*)d_in[4];
  const float* ipW2  = (const float*)d_in[5];
  const float* ipb2  = (const float*)d_in[6];
  const float* consW = (const float*)d_in[7];
  const float* consb = (const float*)d_in[8];
  const float* refp  = (const float*)d_in[9];
  const float* objp  = (const float*)d_in[10];
  const float* retW  = (const float*)d_in[11];
  const float* retb  = (const float*)d_in[12];
  float* out = (float*)d_out;
  char* ws = (char*)d_ws;
  // ws layout (bytes)
  ushort* W1T = (ushort*)(ws);             // 256 x 3200   (1,638,400 B)
  ushort* W2T = (ushort*)(ws + 1638400);   // 128 x 256    (65,536 B)
  ushort* CWT = (ushort*)(ws + 1703936);   // 12 x 128x128 (393,216 B)
  ushort* RWT = (ushort*)(ws + 2097152);   // 14 x 128x128 (458,752 B)
  ushort* MT  = (ushort*)(ws + 2555904);   // 14 x 128x128 (458,752 B)
  ushort* H1  = (ushort*)(ws + 3014656);   // 16384 x 256  (8,388,608 B)
  ushort* ST  = (ushort*)(ws + 11403264);  // 16384 x 128  (4,194,304 B)

  k_transpose<<<dim3(4, 50, 1), dim3(64, 4), 0, stream>>>(ipW1, W1T, 3200, 256);
  k_transpose<<<dim3(2, 4, 1), dim3(64, 4), 0, stream>>>(ipW2, W2T, 256, 128);
  k_transpose<<<dim3(2, 2, 12), dim3(64, 4), 0, stream>>>(consW, CWT, 128, 128);
  k_transpose<<<dim3(2, 2, 14), dim3(64, 4), 0, stream>>>(retW, RWT, 128, 128);
  k_build_mt<<<dim3(16, 14), 128, 0, stream>>>(refp, objp, MT);
  k_gemm1<<<512, 256, 0, stream>>>(sup, anom, ind, W1T, ipb1, H1);
  k_cons<<<256, 256, 0, stream>>>(H1, W2T, CWT, ipb2, consb, ST);
  k_banks<<<256, 256, 0, stream>>>(ST, anom, MT, RWT, retb, out);
}

// Round 3
// 548.505 us; speedup vs baseline: 1.0733x; 1.0733x over previous
//
#include <hip/hip_runtime.h>
#include <stdint.h>

// ---------------------------------------------------------------------------
// HolographicThoracicMemory on MI355X (gfx950)
// interference_weight[b,k] = s^T M_k s, M_k = (0.756/256) sum_c ref⊗obj
// All GEMMs via mfma_f32_16x16x32_bf16 (fp32 accumulate).
// R3: occupancy + pipelining. gemm1: grid(2,512)=1024 blocks (4/CU), dbuf
// As/Bs, ONE barrier/iter, X reg-prefetch. cons/banks: 32 rows, grid 512.
// ---------------------------------------------------------------------------

typedef __attribute__((ext_vector_type(4))) float f32x4;
typedef __attribute__((ext_vector_type(8))) short s16x8;

#define SCALE_IW 0.002953125f  // 0.42 * 1.8 / 256

__device__ __forceinline__ ushort f2bf(float f) {
  uint32_t u = __builtin_bit_cast(uint32_t, f);
  u += 0x7fffu + ((u >> 16) & 1u);
  return (ushort)(u >> 16);
}
__device__ __forceinline__ float bf2f(ushort u) {
  return __builtin_bit_cast(float, ((uint32_t)u) << 16);
}
__device__ __forceinline__ void gl_lds16(const ushort* g, ushort* l) {
  __builtin_amdgcn_global_load_lds(
      (const __attribute__((address_space(1))) uint32_t*)g,
      (__attribute__((address_space(3))) uint32_t*)l, 16, 0, 0);
}
__device__ __forceinline__ f32x4 mfma16(s16x8 a, s16x8 b, f32x4 c) {
  return __builtin_amdgcn_mfma_f32_16x16x32_bf16(a, b, c, 0, 0, 0);
}

// ---------------------------------------------------------------------------
__global__ __launch_bounds__(256) void k_transpose(const float* __restrict__ src,
                                                   ushort* __restrict__ dst,
                                                   int R, int C) {
  __shared__ float tile[64][65];
  const int s = blockIdx.z;
  src += (size_t)s * R * C;
  dst += (size_t)s * R * C;
  const int c0 = blockIdx.x * 64, r0 = blockIdx.y * 64;
  const int tx = threadIdx.x, ty = threadIdx.y;
  for (int i = ty; i < 64; i += 4)
    tile[i][tx] = src[(size_t)(r0 + i) * C + (c0 + tx)];
  __syncthreads();
  for (int i = ty; i < 64; i += 4)
    dst[(size_t)(c0 + i) * R + (r0 + tx)] = f2bf(tile[tx][i]);
}

// ---------------------------------------------------------------------------
__global__ __launch_bounds__(128) void k_build_mt(const float* __restrict__ ref,
                                                  const float* __restrict__ obj,
                                                  ushort* __restrict__ mt) {
  const int k = blockIdx.y, e0 = blockIdx.x * 8, d = threadIdx.x;
  const float* rp = ref + (size_t)k * 256 * 128;
  const float* op = obj + (size_t)k * 256 * 128;
  float acc[8] = {};
  for (int c = 0; c < 256; ++c) {
    const float rv = rp[c * 128 + d];
#pragma unroll
    for (int j = 0; j < 8; ++j) acc[j] += rv * op[c * 128 + e0 + j];
  }
  ushort* o = mt + (size_t)k * 128 * 128;
#pragma unroll
  for (int j = 0; j < 8; ++j) o[(e0 + j) * 128 + d] = f2bf(acc[j] * SCALE_IW);
}

// ---------------------------------------------------------------------------
// GEMM1: X[B,3200](fp32, 3 segments) @ W1T[256n][3200k](bf16) -> relu -> H1 bf16
// grid (2 colhalves, 512 rowblocks), block 256. Tile 32 rows x 128 cols.
// K-step 32. Double-buffered As/Bs, ONE __syncthreads per iter, X prefetch.
// ---------------------------------------------------------------------------
__global__ __launch_bounds__(256, 4) void k_gemm1(
    const float* __restrict__ sup, const float* __restrict__ anom,
    const float* __restrict__ ind, const ushort* __restrict__ w1t,
    const float* __restrict__ b1, ushort* __restrict__ h1) {
  __shared__ alignas(16) ushort As[2][32 * 40];       // [row][k] pad->40
  __shared__ alignas(16) ushort Bs[2][4 * 128 * 8];   // [kc][n][8]
  const int t = threadIdx.x;
  const int w = t >> 6, l = t & 63, m = l & 15, q = l >> 4;
  const int n0 = blockIdx.x * 128;
  const int b0 = blockIdx.y * 32;
  const int ar = t >> 3, ac = t & 7;
  const ushort* wbase = w1t + (size_t)n0 * 3200;
  f32x4 acc[2][2] = {};
  float4 xr;

#define XLOAD(KS, DST)                                                  \
  {                                                                     \
    const int k0_ = (KS) * 32;                                          \
    const float* src_;                                                  \
    int rs_, ko_;                                                       \
    if (k0_ < 1024)      { src_ = sup;  rs_ = 1024; ko_ = k0_; }        \
    else if (k0_ < 1152) { src_ = anom; rs_ = 128;  ko_ = k0_ - 1024; } \
    else                 { src_ = ind;  rs_ = 2048; ko_ = k0_ - 1152; } \
    DST = *(const float4*)(src_ + (size_t)(b0 + ar) * rs_ + ko_ + ac * 4); \
  }
#define STAGE_A(BUF, V)                                       \
  {                                                           \
    uint2 pk_;                                                \
    pk_.x = (uint)f2bf((V).x) | ((uint)f2bf((V).y) << 16);    \
    pk_.y = (uint)f2bf((V).z) | ((uint)f2bf((V).w) << 16);    \
    *(uint2*)(As[BUF] + ar * 40 + ac * 4) = pk_;              \
  }
#define STAGE_B(KS, BUF)                                                   \
  {                                                                        \
    const int k0_ = (KS) * 32;                                             \
    _Pragma("unroll")                                                      \
    for (int i_ = 0; i_ < 2; ++i_) {                                       \
      const int s_ = i_ * 256 + t, c_ = s_ >> 7, n_ = s_ & 127;            \
      gl_lds16(wbase + (size_t)n_ * 3200 + k0_ + c_ * 8,                   \
               Bs[BUF] + c_ * 1024 + n_ * 8);                              \
    }                                                                      \
  }

  XLOAD(0, xr);
  STAGE_A(0, xr);
  STAGE_B(0, 0);
  XLOAD(1, xr);
  for (int ks = 0; ks < 100; ++ks) {
    __syncthreads();  // buf[ks&1] staged (writes drained here); prev reads done
    const int cur = ks & 1, nxt = cur ^ 1;
    if (ks < 99) {
      STAGE_A(nxt, xr);
      STAGE_B(ks + 1, nxt);
      if (ks < 98) XLOAD(ks + 2, xr);
    }
    s16x8 af[2], bf[2];
#pragma unroll
    for (int rt = 0; rt < 2; ++rt)
      af[rt] = *(const s16x8*)(As[cur] + (rt * 16 + m) * 40 + q * 8);
#pragma unroll
    for (int ct = 0; ct < 2; ++ct)
      bf[ct] = *(const s16x8*)(Bs[cur] + q * 1024 + (w * 32 + ct * 16 + m) * 8);
#pragma unroll
    for (int rt = 0; rt < 2; ++rt)
#pragma unroll
      for (int ct = 0; ct < 2; ++ct)
        acc[rt][ct] = mfma16(af[rt], bf[ct], acc[rt][ct]);
  }
#undef XLOAD
#undef STAGE_A
#undef STAGE_B
#pragma unroll
  for (int ct = 0; ct < 2; ++ct) {
    const int col = n0 + w * 32 + ct * 16 + m;
    const float bias = b1[col];
#pragma unroll
    for (int rt = 0; rt < 2; ++rt)
#pragma unroll
      for (int r = 0; r < 4; ++r) {
        const int row = b0 + rt * 16 + q * 4 + r;
        h1[(size_t)row * 256 + col] = f2bf(fmaxf(acc[rt][ct][r] + bias, 0.f));
      }
  }
}

// ---------------------------------------------------------------------------
// Consolidator: H1[B,256]->relu(@W2+b2)->12x relu(@Wl+bl)->state[B,128] bf16
// grid 512 (32 rows/block), block 256 = 4 waves; wave tile 32x32.
// ---------------------------------------------------------------------------
__global__ __launch_bounds__(256, 2) void k_cons(
    const ushort* __restrict__ h1, const ushort* __restrict__ w2t,
    const ushort* __restrict__ cwt, const float* __restrict__ b2,
    const float* __restrict__ cb, ushort* __restrict__ stateg) {
  __shared__ alignas(16) ushort A0[32 * 264];
  __shared__ alignas(16) ushort S0[32 * 136];
  __shared__ alignas(16) ushort S1[32 * 136];
  __shared__ alignas(16) ushort Wb[16 * 128 * 8];  // 32 KB
  const int t = threadIdx.x;
  const int w = t >> 6, l = t & 63, m = l & 15, q = l >> 4;
  const int b0 = blockIdx.x * 32;
#pragma unroll
  for (int i = 0; i < 4; ++i) {
    const int s = i * 256 + t, r = s >> 5, c = s & 31;
    *(uint4*)(A0 + r * 264 + c * 8) =
        *(const uint4*)(h1 + (size_t)(b0 + r) * 256 + c * 8);
  }
  for (int layer = 0; layer <= 12; ++layer) {
    const ushort* Asrc;
    int astr, K;
    const ushort* wsrc;
    const float* bias;
    if (layer == 0) {
      Asrc = A0; astr = 264; wsrc = w2t; bias = b2; K = 256;
    } else {
      Asrc = (layer & 1) ? (const ushort*)S0 : (const ushort*)S1;
      astr = 136;
      wsrc = cwt + (size_t)(layer - 1) * 16384;
      bias = cb + (layer - 1) * 128; K = 128;
    }
    ushort* dst = (layer & 1) ? S1 : S0;
    f32x4 acc[2][2] = {};
    const int halves = K >> 7;
    for (int h = 0; h < halves; ++h) {
      __syncthreads();  // WAR on Wb (and S write of prev layer)
#pragma unroll
      for (int i = 0; i < 8; ++i) {
        const int s = i * 256 + t, c = s >> 7, n = s & 127;
        gl_lds16(wsrc + (size_t)n * K + h * 128 + c * 8, Wb + c * 1024 + n * 8);
      }
      __syncthreads();  // Wb ready
#pragma unroll
      for (int ks = 0; ks < 4; ++ks) {
        s16x8 af[2];
        const int koff = h * 128 + (ks * 4 + q) * 8;
#pragma unroll
        for (int rt = 0; rt < 2; ++rt)
          af[rt] = *(const s16x8*)(Asrc + (rt * 16 + m) * astr + koff);
#pragma unroll
        for (int ct = 0; ct < 2; ++ct) {
          const s16x8 bf =
              *(const s16x8*)(Wb + (ks * 4 + q) * 1024 + (w * 32 + ct * 16 + m) * 8);
#pragma unroll
          for (int rt = 0; rt < 2; ++rt)
            acc[rt][ct] = mfma16(af[rt], bf, acc[rt][ct]);
        }
      }
    }
    __syncthreads();  // all reads of S_prev done before overwriting dst
#pragma unroll
    for (int ct = 0; ct < 2; ++ct) {
      const int col = w * 32 + ct * 16 + m;
      const float bv = bias[col];
#pragma unroll
      for (int rt = 0; rt < 2; ++rt)
#pragma unroll
        for (int r = 0; r < 4; ++r)
          dst[(rt * 16 + q * 4 + r) * 136 + col] =
              f2bf(fmaxf(acc[rt][ct][r] + bv, 0.f));
    }
  }
  __syncthreads();
  const ushort* fin = S0;  // layer 12 (even) wrote S0
#pragma unroll
  for (int i = 0; i < 2; ++i) {
    const int s = i * 256 + t, r = s >> 4, c = s & 15;
    *(uint4*)(stateg + (size_t)(b0 + r) * 128 + c * 8) =
        *(const uint4*)(fin + r * 136 + c * 8);
  }
}

// ---------------------------------------------------------------------------
// Banks: per k: P=S@MT_k (iw = s^T M_k s), R=S@retWT_k;
//   out[b,k,e] = (iw + 0.3*mean|anom_b|) * (R[b,e] + ret_b[k,e])
// grid 512 (32 rows/block), block 256 = 4 waves; wave tile 32x32 per panel.
// ---------------------------------------------------------------------------
__global__ __launch_bounds__(256, 2) void k_banks(
    const ushort* __restrict__ stateg, const float* __restrict__ anom,
    const ushort* __restrict__ mt, const ushort* __restrict__ rwt,
    const float* __restrict__ retb, float* __restrict__ out) {
  __shared__ alignas(16) ushort S[32 * 136];
  __shared__ alignas(16) ushort Mb[16 * 128 * 8];  // 32 KB
  __shared__ alignas(16) ushort Rb[16 * 128 * 8];  // 32 KB
  __shared__ alignas(16) float iwbuf[4][32];
  __shared__ alignas(16) float wvs[32];
  __shared__ alignas(16) float aws[32];
  const int t = threadIdx.x;
  const int w = t >> 6, l = t & 63, m = l & 15, q = l >> 4;
  const int b0 = blockIdx.x * 32;
#pragma unroll
  for (int i = 0; i < 2; ++i) {
    const int s = i * 256 + t, r = s >> 4, c = s & 15;
    *(uint4*)(S + r * 136 + c * 8) =
        *(const uint4*)(stateg + (size_t)(b0 + r) * 128 + c * 8);
  }
  {
    const int r = t >> 3, qq = t & 7;  // 8 threads/row, 16 floats each
    float sa = 0.f;
#pragma unroll
    for (int j = 0; j < 4; ++j) {
      const float4 v =
          *(const float4*)(anom + (size_t)(b0 + r) * 128 + qq * 16 + j * 4);
      sa += fabsf(v.x) + fabsf(v.y) + fabsf(v.z) + fabsf(v.w);
    }
    sa += __shfl_xor(sa, 1, 8);
    sa += __shfl_xor(sa, 2, 8);
    sa += __shfl_xor(sa, 4, 8);
    if (qq == 0) aws[r] = sa * (0.3f / 128.f);
  }
  __syncthreads();
  s16x8 af[4][2];  // [ks][rt] persistent state fragments
#pragma unroll
  for (int ks = 0; ks < 4; ++ks)
#pragma unroll
    for (int rt = 0; rt < 2; ++rt)
      af[ks][rt] = *(const s16x8*)(S + (rt * 16 + m) * 136 + (ks * 4 + q) * 8);
  float sc[2][4][2];  // [rt][reg][ct] fp32 state in C-layout lanes
#pragma unroll
  for (int rt = 0; rt < 2; ++rt)
#pragma unroll
    for (int r = 0; r < 4; ++r)
#pragma unroll
      for (int ct = 0; ct < 2; ++ct)
        sc[rt][r][ct] =
            bf2f(S[(rt * 16 + q * 4 + r) * 136 + (w * 32 + ct * 16 + m)]);
  for (int k = 0; k < 14; ++k) {
#pragma unroll
    for (int i = 0; i < 8; ++i) {
      const int s = i * 256 + t, c = s >> 7, n = s & 127;
      gl_lds16(mt + (size_t)k * 16384 + n * 128 + c * 8, Mb + c * 1024 + n * 8);
      gl_lds16(rwt + (size_t)k * 16384 + n * 128 + c * 8, Rb + c * 1024 + n * 8);
    }
    __syncthreads();
    f32x4 P[2][2] = {}, R[2][2] = {};
#pragma unroll
    for (int ks = 0; ks < 4; ++ks)
#pragma unroll
      for (int ct = 0; ct < 2; ++ct) {
        const int boff = (ks * 4 + q) * 1024 + (w * 32 + ct * 16 + m) * 8;
        const s16x8 bm = *(const s16x8*)(Mb + boff);
        const s16x8 br = *(const s16x8*)(Rb + boff);
#pragma unroll
        for (int rt = 0; rt < 2; ++rt) {
          P[rt][ct] = mfma16(af[ks][rt], bm, P[rt][ct]);
          R[rt][ct] = mfma16(af[ks][rt], br, R[rt][ct]);
        }
      }
#pragma unroll
    for (int rt = 0; rt < 2; ++rt) {
      float pr[4];
#pragma unroll
      for (int r = 0; r < 4; ++r) {
        float v = P[rt][0][r] * sc[rt][r][0] + P[rt][1][r] * sc[rt][r][1];
        v += __shfl_xor(v, 1, 16);
        v += __shfl_xor(v, 2, 16);
        v += __shfl_xor(v, 4, 16);
        v += __shfl_xor(v, 8, 16);
        pr[r] = v;
      }
      if (m == 0)
        *(float4*)&iwbuf[w][rt * 16 + q * 4] =
            make_float4(pr[0], pr[1], pr[2], pr[3]);
    }
    __syncthreads();
    if (t < 32) wvs[t] = iwbuf[0][t] + iwbuf[1][t] + iwbuf[2][t] + iwbuf[3][t] + aws[t];
    __syncthreads();
#pragma unroll
    for (int ct = 0; ct < 2; ++ct) {
      const int col = w * 32 + ct * 16 + m;
      const float rb = retb[k * 128 + col];
#pragma unroll
      for (int rt = 0; rt < 2; ++rt) {
        const float4 wv4 = *(const float4*)&wvs[rt * 16 + q * 4];
        const float wvv[4] = {wv4.x, wv4.y, wv4.z, wv4.w};
#pragma unroll
        for (int r = 0; r < 4; ++r) {
          const int row = b0 + rt * 16 + q * 4 + r;
          out[(size_t)row * 1792 + k * 128 + col] = wvv[r] * (R[rt][ct][r] + rb);
        }
      }
    }
    // next-k Mb/Rb staging is ordered after this k's MFMA reads by the two
    // barriers above; epilogue reads only wvs/regs, and the first barrier of
    // k+1's consume phase keeps all waves together.
  }
}

// ---------------------------------------------------------------------------
extern "C" void kernel_launch(void* const* d_in, const int* in_sizes, int n_in,
                              void* d_out, int out_size, void* d_ws,
                              size_t ws_size, hipStream_t stream) {
  const float* sup   = (const float*)d_in[0];
  const float* anom  = (const float*)d_in[1];
  const float* ind   = (const float*)d_in[2];
  const float* ipW1  = (const float*)d_in[3];
  const float* ipb1  = (const float*)d_in[4];
  const float* ipW2  = (const float*)d_in[5];
  const float* ipb2  = (const float*)d_in[6];
  const float* consW = (const float*)d_in[7];
  const float* consb = (const float*)d_in[8];
  const float* refp  = (const float*)d_in[9];
  const float* objp  = (const float*)d_in[10];
  const float* retW  = (const float*)d_in[11];
  const float* retb  = (const float*)d_in[12];
  float* out = (float*)d_out;
  char* ws = (char*)d_ws;
  ushort* W1T = (ushort*)(ws);             // 256 x 3200
  ushort* W2T = (ushort*)(ws + 1638400);   // 128 x 256
  ushort* CWT = (ushort*)(ws + 1703936);   // 12 x 128x128
  ushort* RWT = (ushort*)(ws + 2097152);   // 14 x 128x128
  ushort* MT  = (ushort*)(ws + 2555904);   // 14 x 128x128
  ushort* H1  = (ushort*)(ws + 3014656);   // 16384 x 256 bf16
  ushort* ST  = (ushort*)(ws + 11403264);  // 16384 x 128 bf16

  k_transpose<<<dim3(4, 50, 1), dim3(64, 4), 0, stream>>>(ipW1, W1T, 3200, 256);
  k_transpose<<<dim3(2, 4, 1), dim3(64, 4), 0, stream>>>(ipW2, W2T, 256, 128);
  k_transpose<<<dim3(2, 2, 12), dim3(64, 4), 0, stream>>>(consW, CWT, 128, 128);
  k_transpose<<<dim3(2, 2, 14), dim3(64, 4), 0, stream>>>(retW, RWT, 128, 128);
  k_build_mt<<<dim3(16, 14), 128, 0, stream>>>(refp, objp, MT);
  k_gemm1<<<dim3(2, 512), 256, 0, stream>>>(sup, anom, ind, W1T, ipb1, H1);
  k_cons<<<512, 256, 0, stream>>>(H1, W2T, CWT, ipb2, consb, ST);
  k_banks<<<512, 256, 0, stream>>>(ST, anom, MT, RWT, retb, out);
}